// Round 3
// baseline (1132.762 us; speedup 1.0000x reference)
//
#include <hip/hip_runtime.h>

#define B_  8
#define C_  32
#define H_  128
#define W_  128
#define CO_ 64
#define KK_ 9
#define HW_ (H_*W_)

// launch_bounds(256, 2): min 2 waves/EU -> ~256-VGPR budget. The default
// heuristic picked a 64-reg budget and SPILLED acc[64] to scratch (R0/R1:
// VGPR_Count=60 < 64 accumulators alone -> ~90% stall on scratch RMW).
__global__ __launch_bounds__(256, 2) void dconv_fused(
    const float* __restrict__ x,
    const float* __restrict__ w_off,
    const float* __restrict__ b_off,
    const float* __restrict__ w_mod,
    const float* __restrict__ b_mod,
    const float* __restrict__ w_reg,
    float* __restrict__ out)
{
    const int pix = blockIdx.x * 256 + threadIdx.x;
    const int b  = pix / HW_;
    const int hw = pix % HW_;
    const int h  = hw / W_;
    const int w  = hw % W_;

    // ---------- stage 1: 3x3 conv producing 18 offset + 9 mask channels ----
    float oacc[27];
    #pragma unroll
    for (int j = 0; j < 18; ++j) oacc[j] = b_off[j];
    #pragma unroll
    for (int j = 0; j < 9; ++j)  oacc[18 + j] = b_mod[j];

    const float* xb = x + b * (C_ * HW_);

    for (int c = 0; c < C_; ++c) {
        float xv[9];
        #pragma unroll
        for (int t = 0; t < 9; ++t) {
            const int yy = h + t / 3 - 1;
            const int xx = w + t % 3 - 1;
            const bool ok = (yy >= 0) & (yy < H_) & (xx >= 0) & (xx < W_);
            xv[t] = ok ? xb[c * HW_ + yy * W_ + xx] : 0.0f;
        }
        const float* wo = w_off + c * 9;
        #pragma unroll
        for (int j = 0; j < 18; ++j) {
            #pragma unroll
            for (int t = 0; t < 9; ++t)
                oacc[j] = fmaf(wo[j * (C_ * 9) + t], xv[t], oacc[j]);
        }
        const float* wm = w_mod + c * 9;
        #pragma unroll
        for (int j = 0; j < 9; ++j) {
            #pragma unroll
            for (int t = 0; t < 9; ++t)
                oacc[18 + j] = fmaf(wm[j * (C_ * 9) + t], xv[t], oacc[18 + j]);
        }
    }

    // ---------- stage 2+3: bilinear sampling (validity+mask folded into
    // weights) and the o-c-kk einsum, ALL 64 accumulators in registers ------
    float acc[CO_];
    #pragma unroll
    for (int o = 0; o < CO_; ++o) acc[o] = 0.0f;

    #pragma unroll   // MUST unroll: oacc[] indexed by kk (avoid scratch)
    for (int kk = 0; kk < KK_; ++kk) {
        const int ky = kk / 3, kx = kk % 3;
        const float offy = fminf(fmaxf(oacc[kk * 2 + 0], -32.0f), 32.0f);
        const float offx = fminf(fmaxf(oacc[kk * 2 + 1], -32.0f), 32.0f);
        const float m = 2.0f / (1.0f + expf(-oacc[18 + kk]));

        const float py = offy + (float)(h - 1 + ky);
        const float px = offx + (float)(w - 1 + kx);
        const float y0f = floorf(py);
        const float x0f = floorf(px);
        const float dy = py - y0f;
        const float dx = px - x0f;
        const int y0 = (int)y0f, x0 = (int)x0f;
        const int y1 = y0 + 1,  x1 = x0 + 1;

        const bool vy0 = (y0 >= 0) & (y0 < H_);
        const bool vy1 = (y1 >= 0) & (y1 < H_);
        const bool vx0 = (x0 >= 0) & (x0 < W_);
        const bool vx1 = (x1 >= 0) & (x1 < W_);

        const float wm00 = (vy0 & vx0) ? (1.0f - dy) * (1.0f - dx) * m : 0.0f;
        const float wm01 = (vy0 & vx1) ? (1.0f - dy) * dx * m         : 0.0f;
        const float wm10 = (vy1 & vx0) ? dy * (1.0f - dx) * m         : 0.0f;
        const float wm11 = (vy1 & vx1) ? dy * dx * m                  : 0.0f;

        const int y0c = min(max(y0, 0), H_ - 1), y1c = min(max(y1, 0), H_ - 1);
        const int x0c = min(max(x0, 0), W_ - 1), x1c = min(max(x1, 0), W_ - 1);
        const int i00 = y0c * W_ + x0c;
        const int i01 = y0c * W_ + x1c;
        const int i10 = y1c * W_ + x0c;
        const int i11 = y1c * W_ + x1c;

        // 4 channels of gathers batched -> 16 independent loads in flight;
        // unroll 2 lets chunk k+1's loads issue under chunk k's einsum.
        #pragma unroll 2
        for (int c4 = 0; c4 < C_; c4 += 4) {
            float s[4];
            #pragma unroll
            for (int u = 0; u < 4; ++u) {
                const float* xc = xb + (c4 + u) * HW_;
                s[u] = wm00 * xc[i00] + wm01 * xc[i01]
                     + wm10 * xc[i10] + wm11 * xc[i11];
            }
            #pragma unroll
            for (int u = 0; u < 4; ++u) {
                const float* wr = w_reg + (c4 + u) * 9 + kk;  // uniform -> s_load
                #pragma unroll
                for (int o = 0; o < CO_; ++o)
                    acc[o] = fmaf(wr[o * (C_ * 9)], s[u], acc[o]);
            }
        }
    }

    float* ob = out + b * (CO_ * HW_) + hw;
    #pragma unroll
    for (int o = 0; o < CO_; ++o)
        ob[o * HW_] = acc[o];
}

extern "C" void kernel_launch(void* const* d_in, const int* in_sizes, int n_in,
                              void* d_out, int out_size, void* d_ws, size_t ws_size,
                              hipStream_t stream) {
    const float* x     = (const float*)d_in[0];
    const float* w_off = (const float*)d_in[1];
    const float* b_off = (const float*)d_in[2];
    const float* w_mod = (const float*)d_in[3];
    const float* b_mod = (const float*)d_in[4];
    const float* w_reg = (const float*)d_in[5];
    float* out = (float*)d_out;

    dconv_fused<<<B_ * HW_ / 256, 256, 0, stream>>>(x, w_off, b_off, w_mod,
                                                    b_mod, w_reg, out);
}

// Round 4
// 181.814 us; speedup vs baseline: 6.2303x; 6.2303x over previous
//
#include <hip/hip_runtime.h>

#define B_  8
#define C_  32
#define H_  128
#define W_  128
#define CO_ 64
#define KK_ 9
#define HW_ (H_*W_)
#define TP_ 256          // pixels per block

// Structure: per-pixel offset conv (phase A) -> per-kk {gather 32ch -> LDS,
// W chunk -> LDS, barrier, 8x8-register-tiled GEMM step, barrier}.
// Classic SGEMM register tiling: 64 accumulators/thread, constant-indexed
// everywhere -> no scratch (R0-R2 all spilled acc[] in the fused-scalar form).
__global__ __launch_bounds__(256, 2) void dconv_fused(
    const float* __restrict__ x,
    const float* __restrict__ w_off,
    const float* __restrict__ b_off,
    const float* __restrict__ w_mod,
    const float* __restrict__ b_mod,
    const float* __restrict__ w_reg,
    float* __restrict__ out)
{
    __shared__ float OFF[27][TP_];   // 18 offsets + 9 masks, per pixel
    __shared__ float Wl[CO_][C_];    // W chunk for current kk: [o][c]
    __shared__ float Sl[C_][TP_];    // sampled*mask chunk: [c][pix]

    const int tid = threadIdx.x;
    const int pixbase = blockIdx.x * TP_;        // 256 consecutive pixels, one b
    const int pix = pixbase + tid;
    const int b  = pix / HW_;
    const int hw = pix % HW_;
    const int h  = hw / W_;
    const int w  = hw % W_;
    const float* xb = x + b * (C_ * HW_);

    // ---------- phase A: 3x3 conv -> 18 offsets (clamped) + 9 masks --------
    {
        float oacc[27];
        #pragma unroll
        for (int j = 0; j < 18; ++j) oacc[j] = b_off[j];
        #pragma unroll
        for (int j = 0; j < 9; ++j)  oacc[18 + j] = b_mod[j];

        for (int c = 0; c < C_; ++c) {
            float xv[9];
            #pragma unroll
            for (int t = 0; t < 9; ++t) {
                const int yy = h + t / 3 - 1;
                const int xx = w + t % 3 - 1;
                const bool ok = (yy >= 0) & (yy < H_) & (xx >= 0) & (xx < W_);
                xv[t] = ok ? xb[c * HW_ + yy * W_ + xx] : 0.0f;
            }
            const float* wo = w_off + c * 9;
            #pragma unroll
            for (int j = 0; j < 18; ++j) {
                #pragma unroll
                for (int t = 0; t < 9; ++t)
                    oacc[j] = fmaf(wo[j * (C_ * 9) + t], xv[t], oacc[j]);
            }
            const float* wm = w_mod + c * 9;
            #pragma unroll
            for (int j = 0; j < 9; ++j) {
                #pragma unroll
                for (int t = 0; t < 9; ++t)
                    oacc[18 + j] = fmaf(wm[j * (C_ * 9) + t], xv[t], oacc[18 + j]);
            }
        }
        #pragma unroll
        for (int j = 0; j < 18; ++j)
            OFF[j][tid] = fminf(fmaxf(oacc[j], -32.0f), 32.0f);
        #pragma unroll
        for (int j = 0; j < 9; ++j)
            OFF[18 + j][tid] = 2.0f / (1.0f + expf(-oacc[18 + j]));
        // self-read only below -> no barrier needed here
    }

    // ---------- per-kk: stage S,W chunks then GEMM step --------------------
    float acc[8][8];
    #pragma unroll
    for (int oi = 0; oi < 8; ++oi)
        #pragma unroll
        for (int pj = 0; pj < 8; ++pj) acc[oi][pj] = 0.0f;

    const int to = tid >> 5;   // o-tile   : o  = to*8 + oi
    const int tp = tid & 31;   // pix-tile : px = tp*8 + pj

    for (int kk = 0; kk < KK_; ++kk) {
        // W chunk: Wl[o][c] = w_reg[(o*C_+c)*9 + kk]; lanes sweep c -> LDS
        // writes conflict-free, global reads stride-36B (tiny, L2-resident)
        #pragma unroll
        for (int i = 0; i < 8; ++i) {
            const int idx = i * 256 + tid;       // 0..2047
            const int o = idx >> 5, c = idx & 31;
            Wl[o][c] = w_reg[(o * C_ + c) * 9 + kk];
        }

        // bilinear weights for my pixel at this kernel position
        const int ky = kk / 3, kx = kk % 3;
        const float offy = OFF[kk * 2 + 0][tid];
        const float offx = OFF[kk * 2 + 1][tid];
        const float m    = OFF[18 + kk][tid];

        const float py = offy + (float)(h - 1 + ky);
        const float px = offx + (float)(w - 1 + kx);
        const float y0f = floorf(py);
        const float x0f = floorf(px);
        const float dy = py - y0f;
        const float dx = px - x0f;
        const int y0 = (int)y0f, x0 = (int)x0f;
        const int y1 = y0 + 1,  x1 = x0 + 1;

        const bool vy0 = (y0 >= 0) & (y0 < H_);
        const bool vy1 = (y1 >= 0) & (y1 < H_);
        const bool vx0 = (x0 >= 0) & (x0 < W_);
        const bool vx1 = (x1 >= 0) & (x1 < W_);

        const float wm00 = (vy0 & vx0) ? (1.0f - dy) * (1.0f - dx) * m : 0.0f;
        const float wm01 = (vy0 & vx1) ? (1.0f - dy) * dx * m         : 0.0f;
        const float wm10 = (vy1 & vx0) ? dy * (1.0f - dx) * m         : 0.0f;
        const float wm11 = (vy1 & vx1) ? dy * dx * m                  : 0.0f;

        const int y0c = min(max(y0, 0), H_ - 1), y1c = min(max(y1, 0), H_ - 1);
        const int x0c = min(max(x0, 0), W_ - 1), x1c = min(max(x1, 0), W_ - 1);
        const int i00 = y0c * W_ + x0c;
        const int i01 = y0c * W_ + x1c;
        const int i10 = y1c * W_ + x0c;
        const int i11 = y1c * W_ + x1c;

        // gather 32 channels (4 at a time: 16 loads in flight) -> Sl[c][pix]
        #pragma unroll
        for (int c4 = 0; c4 < C_; c4 += 4) {
            float s[4];
            #pragma unroll
            for (int u = 0; u < 4; ++u) {
                const float* xc = xb + (c4 + u) * HW_;
                s[u] = wm00 * xc[i00] + wm01 * xc[i01]
                     + wm10 * xc[i10] + wm11 * xc[i11];
            }
            #pragma unroll
            for (int u = 0; u < 4; ++u)
                Sl[c4 + u][tid] = s[u];
        }

        __syncthreads();

        // GEMM step: acc[8][8] += Wl[to*8+oi][k] * Sl[k][tp*8+pj], k=0..31
        #pragma unroll 4
        for (int k = 0; k < 32; ++k) {
            const float4 sA = *(const float4*)&Sl[k][tp * 8];
            const float4 sB = *(const float4*)&Sl[k][tp * 8 + 4];
            const float sv[8] = {sA.x, sA.y, sA.z, sA.w, sB.x, sB.y, sB.z, sB.w};
            #pragma unroll
            for (int oi = 0; oi < 8; ++oi) {
                const float wv = Wl[to * 8 + oi][k];   // broadcast per half-wave
                #pragma unroll
                for (int pj = 0; pj < 8; ++pj)
                    acc[oi][pj] = fmaf(wv, sv[pj], acc[oi][pj]);
            }
        }

        __syncthreads();   // protect Sl/Wl before next kk overwrites
    }

    // ---------- epilogue: write 8x8 tile, float4-vectorized ----------------
    const int hwbase = pixbase % HW_;
    float* ob = out + (size_t)b * (CO_ * HW_) + hwbase + tp * 8;
    #pragma unroll
    for (int oi = 0; oi < 8; ++oi) {
        float* row = ob + (to * 8 + oi) * HW_;
        *(float4*)(row)     = make_float4(acc[oi][0], acc[oi][1], acc[oi][2], acc[oi][3]);
        *(float4*)(row + 4) = make_float4(acc[oi][4], acc[oi][5], acc[oi][6], acc[oi][7]);
    }
}

extern "C" void kernel_launch(void* const* d_in, const int* in_sizes, int n_in,
                              void* d_out, int out_size, void* d_ws, size_t ws_size,
                              hipStream_t stream) {
    const float* x     = (const float*)d_in[0];
    const float* w_off = (const float*)d_in[1];
    const float* b_off = (const float*)d_in[2];
    const float* w_mod = (const float*)d_in[3];
    const float* b_mod = (const float*)d_in[4];
    const float* w_reg = (const float*)d_in[5];
    float* out = (float*)d_out;
    (void)d_ws; (void)ws_size;

    dconv_fused<<<B_ * HW_ / TP_, 256, 0, stream>>>(x, w_off, b_off, w_mod,
                                                    b_mod, w_reg, out);
}

// Round 5
// 162.116 us; speedup vs baseline: 6.9873x; 1.1215x over previous
//
#include <hip/hip_runtime.h>
#include <hip/hip_bf16.h>

#define B_  8
#define C_  32
#define H_  128
#define W_  128
#define CO_ 64
#define KK_ 9
#define HW_ (H_*W_)
#define TP_ 256          // pixels per block

typedef short s16x8 __attribute__((ext_vector_type(8)));   // 8 bf16 operand
typedef float f32x4 __attribute__((ext_vector_type(4)));   // MFMA accumulator

__device__ __forceinline__ short bf16b(float f) {
    __hip_bfloat16 h = __float2bfloat16(f);
    return __builtin_bit_cast(short, h);
}

// Per kk: OUT[64 x 256] += W9[64 x 32] * S[32 x 256], K=32 -> one
// mfma_f32_16x16x32_bf16 per 16x16 tile; 4 waves x (4 o-tiles x 4 p-tiles).
// Fragment layouts (m89/m91-verified convention):
//   A lane l: A[l&15][(l>>4)*8+j]   -> Wl[kg][o][8] bf16, one ds_read_b128
//   B lane l: B[(l>>4)*8+j][l&15]   -> Sl[kg][pix][8] bf16, one ds_read_b128
//   D lane l: D[(l>>4)*4+j][l&15]
__global__ __launch_bounds__(256, 3) void dconv_fused(
    const float* __restrict__ x,
    const float* __restrict__ w_off,
    const float* __restrict__ b_off,
    const float* __restrict__ w_mod,
    const float* __restrict__ b_mod,
    const float* __restrict__ w_reg,
    float* __restrict__ out)
{
    __shared__ float OFF[27][TP_];      // 18 clamped offsets + 9 masks  (27.6KB)
    __shared__ short Sl[4][TP_][8];     // bf16 samples, kg-major        (16KB)
    __shared__ short Wl[4][CO_][8];     // bf16 W chunk for current kk   (4KB)

    const int tid = threadIdx.x;
    const int pixbase = blockIdx.x * TP_;   // one b, 2 image rows per block
    const int bidx = pixbase / HW_;
    const int hwbase = pixbase % HW_;
    const int hw = hwbase + tid;
    const int h  = hw / W_;
    const int w  = hw % W_;
    const float* xb = x + bidx * (C_ * HW_);

    // ---------- phase A: 3x3 conv -> 18 offsets (clamped) + 9 masks --------
    {
        float oacc[27];
        #pragma unroll
        for (int j = 0; j < 18; ++j) oacc[j] = b_off[j];
        #pragma unroll
        for (int j = 0; j < 9; ++j)  oacc[18 + j] = b_mod[j];

        for (int c = 0; c < C_; ++c) {
            float xv[9];
            #pragma unroll
            for (int t = 0; t < 9; ++t) {
                const int yy = h + t / 3 - 1;
                const int xx = w + t % 3 - 1;
                const bool ok = (yy >= 0) & (yy < H_) & (xx >= 0) & (xx < W_);
                xv[t] = ok ? xb[c * HW_ + yy * W_ + xx] : 0.0f;
            }
            const float* wo = w_off + c * 9;
            #pragma unroll
            for (int j = 0; j < 18; ++j) {
                #pragma unroll
                for (int t = 0; t < 9; ++t)
                    oacc[j] = fmaf(wo[j * (C_ * 9) + t], xv[t], oacc[j]);
            }
            const float* wm = w_mod + c * 9;
            #pragma unroll
            for (int j = 0; j < 9; ++j) {
                #pragma unroll
                for (int t = 0; t < 9; ++t)
                    oacc[18 + j] = fmaf(wm[j * (C_ * 9) + t], xv[t], oacc[18 + j]);
            }
        }
        #pragma unroll
        for (int j = 0; j < 18; ++j)
            OFF[j][tid] = fminf(fmaxf(oacc[j], -32.0f), 32.0f);
        #pragma unroll
        for (int j = 0; j < 9; ++j)
            OFF[18 + j][tid] = 2.0f / (1.0f + expf(-oacc[18 + j]));
        // self-read only -> no barrier
    }

    const int lane = tid & 63;
    const int wid  = tid >> 6;        // wave id: p-tiles [wid*4 .. wid*4+3]
    const int fr   = lane & 15;
    const int fq   = lane >> 4;

    f32x4 acc[4][4];                  // [o-tile][p-tile]
    #pragma unroll
    for (int ot = 0; ot < 4; ++ot)
        #pragma unroll
        for (int pt = 0; pt < 4; ++pt)
            acc[ot][pt] = (f32x4){0.f, 0.f, 0.f, 0.f};

    for (int kk = 0; kk < KK_; ++kk) {
        // ---- stage W chunk: Wl[kg][o][j] = w_reg[(o*32 + kg*8+j)*9 + kk] --
        {
            const int kg = tid >> 6, o = tid & 63;
            s16x8 wv;
            #pragma unroll
            for (int j = 0; j < 8; ++j)
                wv[j] = bf16b(w_reg[(o * C_ + kg * 8 + j) * 9 + kk]);
            *(s16x8*)&Wl[kg][o][0] = wv;
        }

        // ---- bilinear weights for my pixel at this kernel position --------
        const int ky = kk / 3, kx = kk % 3;
        const float offy = OFF[kk * 2 + 0][tid];
        const float offx = OFF[kk * 2 + 1][tid];
        const float m    = OFF[18 + kk][tid];

        const float py = offy + (float)(h - 1 + ky);
        const float px = offx + (float)(w - 1 + kx);
        const float y0f = floorf(py);
        const float x0f = floorf(px);
        const float dy = py - y0f;
        const float dx = px - x0f;
        const int y0 = (int)y0f, x0 = (int)x0f;
        const int y1 = y0 + 1,  x1 = x0 + 1;

        const bool vy0 = (y0 >= 0) & (y0 < H_);
        const bool vy1 = (y1 >= 0) & (y1 < H_);
        const bool vx0 = (x0 >= 0) & (x0 < W_);
        const bool vx1 = (x1 >= 0) & (x1 < W_);

        const float wm00 = (vy0 & vx0) ? (1.0f - dy) * (1.0f - dx) * m : 0.0f;
        const float wm01 = (vy0 & vx1) ? (1.0f - dy) * dx * m         : 0.0f;
        const float wm10 = (vy1 & vx0) ? dy * (1.0f - dx) * m         : 0.0f;
        const float wm11 = (vy1 & vx1) ? dy * dx * m                  : 0.0f;

        const int y0c = min(max(y0, 0), H_ - 1), y1c = min(max(y1, 0), H_ - 1);
        const int x0c = min(max(x0, 0), W_ - 1), x1c = min(max(x1, 0), W_ - 1);
        const int i00 = y0c * W_ + x0c;
        const int i01 = y0c * W_ + x1c;
        const int i10 = y1c * W_ + x0c;
        const int i11 = y1c * W_ + x1c;

        // ---- gather all 32 channels (fully unrolled: 32 loads in flight) --
        float s[C_];
        #pragma unroll
        for (int c4 = 0; c4 < C_; c4 += 4) {
            #pragma unroll
            for (int u = 0; u < 4; ++u) {
                const float* xc = xb + (c4 + u) * HW_;
                s[c4 + u] = wm00 * xc[i00] + wm01 * xc[i01]
                          + wm10 * xc[i10] + wm11 * xc[i11];
            }
        }
        // ---- pack to bf16, kg-major: Sl[kg][pix][j] = s[kg*8+j] -----------
        #pragma unroll
        for (int kg = 0; kg < 4; ++kg) {
            s16x8 v;
            #pragma unroll
            for (int j = 0; j < 8; ++j) v[j] = bf16b(s[kg * 8 + j]);
            *(s16x8*)&Sl[kg][tid][0] = v;
        }

        __syncthreads();

        // ---- MFMA step: 4 a-frags + 4 b-frags, 16 MFMAs -------------------
        s16x8 af[4], bfg[4];
        #pragma unroll
        for (int ot = 0; ot < 4; ++ot)
            af[ot] = *(const s16x8*)&Wl[fq][ot * 16 + fr][0];
        #pragma unroll
        for (int pt = 0; pt < 4; ++pt)
            bfg[pt] = *(const s16x8*)&Sl[fq][wid * 64 + pt * 16 + fr][0];

        #pragma unroll
        for (int ot = 0; ot < 4; ++ot)
            #pragma unroll
            for (int pt = 0; pt < 4; ++pt)
                acc[ot][pt] = __builtin_amdgcn_mfma_f32_16x16x32_bf16(
                                  af[ot], bfg[pt], acc[ot][pt], 0, 0, 0);

        __syncthreads();   // protect Sl/Wl before next kk overwrites
    }

    // ---------- epilogue: D lane l -> o = ot*16+fq*4+j, pix = wid*64+pt*16+fr
    float* outb = out + (size_t)bidx * (CO_ * HW_) + hwbase;
    #pragma unroll
    for (int ot = 0; ot < 4; ++ot) {
        #pragma unroll
        for (int j = 0; j < 4; ++j) {
            const int o = ot * 16 + fq * 4 + j;
            float* row = outb + o * HW_ + wid * 64 + fr;
            #pragma unroll
            for (int pt = 0; pt < 4; ++pt)
                row[pt * 16] = acc[ot][pt][j];
        }
    }
}

extern "C" void kernel_launch(void* const* d_in, const int* in_sizes, int n_in,
                              void* d_out, int out_size, void* d_ws, size_t ws_size,
                              hipStream_t stream) {
    const float* x     = (const float*)d_in[0];
    const float* w_off = (const float*)d_in[1];
    const float* b_off = (const float*)d_in[2];
    const float* w_mod = (const float*)d_in[3];
    const float* b_mod = (const float*)d_in[4];
    const float* w_reg = (const float*)d_in[5];
    float* out = (float*)d_out;
    (void)d_ws; (void)ws_size;

    dconv_fused<<<B_ * HW_ / TP_, 256, 0, stream>>>(x, w_off, b_off, w_mod,
                                                    b_mod, w_reg, out);
}